// Round 3
// baseline (210.212 us; speedup 1.0000x reference)
//
#include <hip/hip_runtime.h>

// out[b] = -(x[b] . z[b])^2,  z = MLP(x): 64 ->512(ELU)->512(ELU)->256(ELU)->64
// Fused bf16-MFMA kernel: 128 rows/block, 8 waves, intermediates in LDS.

#define DEVI __device__ __forceinline__

typedef __attribute__((ext_vector_type(4))) float f32x4;
typedef __attribute__((ext_vector_type(8))) short bf16x8;

#define PADW 520  // 512 + 8 shorts pad -> row stride 1040B == 4 banks mod 32

DEVI short f2bf(float f) {  // round-to-nearest-even fp32 -> bf16 bits
  unsigned u = __float_as_uint(f);
  u = u + 0x7fffu + ((u >> 16) & 1u);
  return (short)(u >> 16);
}

// One fused conversion kernel: W1|W2|W3|W4 fp32 -> bf16 into contiguous d_ws.
// float4 region bounds: W1 [0,8192) W2 [8192,73728) W3 [73728,106496) W4 [106496,110592)
__global__ void cvtw_all_kernel(const float* __restrict__ W1, const float* __restrict__ W2,
                                const float* __restrict__ W3, const float* __restrict__ W4,
                                short* __restrict__ dst) {
  int i = blockIdx.x * blockDim.x + threadIdx.x;
  if (i >= 110592) return;
  const float* src;
  int off;
  if (i < 8192)        { src = W1; off = 0; }
  else if (i < 73728)  { src = W2; off = 8192; }
  else if (i < 106496) { src = W3; off = 73728; }
  else                 { src = W4; off = 106496; }
  float4 v = reinterpret_cast<const float4*>(src)[i - off];
  short4 o;
  o.x = f2bf(v.x); o.y = f2bf(v.y); o.z = f2bf(v.z); o.w = f2bf(v.w);
  reinterpret_cast<short4*>(dst)[i] = o;
}

// Generic hidden layer, wave grid 2x4 over [128 rows][64*NCT cols].
// A-frag: lane l -> row (l&15), k = (l>>4)*8 + j   (m92 layout, B^T weights)
// D: col = lane&15, row = (lane>>4)*4 + j          (m89/m91)
template<int K, int NCT, bool DO_ELU>
DEVI void mlp_layer(const short* __restrict__ Wb, const float* __restrict__ bias,
                    short (&hb)[128][PADW], int wm, int wn, int lane) {
  const int lr = lane & 15, kg = lane >> 4;
  const int r0 = wm * 64;            // 4 row-tiles of 16
  const int c0 = wn * (NCT * 16);    // NCT col-tiles of 16
  f32x4 acc[4][NCT] = {};
  for (int ks = 0; ks < K / 32; ++ks) {
    const int kk = ks * 32 + kg * 8;
    bf16x8 a[4], b[NCT];
#pragma unroll
    for (int rt = 0; rt < 4; ++rt)
      a[rt] = *reinterpret_cast<const bf16x8*>(&hb[r0 + rt * 16 + lr][kk]);
#pragma unroll
    for (int ct = 0; ct < NCT; ++ct)
      b[ct] = *reinterpret_cast<const bf16x8*>(&Wb[(c0 + ct * 16 + lr) * K + kk]);
#pragma unroll
    for (int rt = 0; rt < 4; ++rt)
#pragma unroll
      for (int ct = 0; ct < NCT; ++ct)
        acc[rt][ct] = __builtin_amdgcn_mfma_f32_16x16x32_bf16(a[rt], b[ct], acc[rt][ct], 0, 0, 0);
  }
  __syncthreads();  // all waves done reading input region before in-place overwrite
#pragma unroll
  for (int ct = 0; ct < NCT; ++ct) {
    const int col = c0 + ct * 16 + lr;
    const float bv = bias[col];
#pragma unroll
    for (int rt = 0; rt < 4; ++rt) {
#pragma unroll
      for (int j = 0; j < 4; ++j) {
        float v = acc[rt][ct][j] + bv;
        if (DO_ELU) v = v > 0.f ? v : (__expf(v) - 1.f);
        hb[r0 + rt * 16 + kg * 4 + j][col] = f2bf(v);
      }
    }
  }
  __syncthreads();  // outputs visible to all waves
}

// Layer 4 (256->64, no ELU) + fused dot with fp32 x + write -(dot)^2.
// Wave grid 8x1: wave owns 16 rows x all 64 cols.
DEVI void final_layer(const short* __restrict__ W4b, const float* __restrict__ b4,
                      const float* __restrict__ xg, float* __restrict__ out,
                      short (&hb)[128][PADW], int wid, int lane, int R0) {
  const int lr = lane & 15, kg = lane >> 4;
  const int r0 = wid * 16;
  f32x4 acc[4] = {};
  for (int ks = 0; ks < 8; ++ks) {
    const int kk = ks * 32 + kg * 8;
    bf16x8 a = *reinterpret_cast<const bf16x8*>(&hb[r0 + lr][kk]);
#pragma unroll
    for (int ct = 0; ct < 4; ++ct) {
      bf16x8 b = *reinterpret_cast<const bf16x8*>(&W4b[(ct * 16 + lr) * 256 + kk]);
      acc[ct] = __builtin_amdgcn_mfma_f32_16x16x32_bf16(a, b, acc[ct], 0, 0, 0);
    }
  }
  float bv[4];
#pragma unroll
  for (int ct = 0; ct < 4; ++ct) bv[ct] = b4[ct * 16 + lr];
#pragma unroll
  for (int j = 0; j < 4; ++j) {
    const int gr = R0 + r0 + kg * 4 + j;  // global batch row
    float p = 0.f;
#pragma unroll
    for (int ct = 0; ct < 4; ++ct)
      p += (acc[ct][j] + bv[ct]) * xg[gr * 64 + ct * 16 + lr];
    p += __shfl_xor(p, 1);
    p += __shfl_xor(p, 2);
    p += __shfl_xor(p, 4);
    p += __shfl_xor(p, 8);
    if (lr == 0) out[gr] = -p * p;
  }
}

__global__ __launch_bounds__(512, 2)
void mlp_fused_kernel(const float* __restrict__ x,
                      const short* __restrict__ Wb,
                      const float* __restrict__ b1, const float* __restrict__ b2,
                      const float* __restrict__ b3, const float* __restrict__ b4,
                      float* __restrict__ out) {
  __shared__ __align__(16) short hb[128][PADW];
  const int tid = threadIdx.x;
  const int lane = tid & 63, wid = tid >> 6;
  const int wm = wid >> 2, wn = wid & 3;
  const int R0 = blockIdx.x * 128;

  // Stage x tile -> bf16 LDS [128][64] (coalesced float4 loads)
#pragma unroll
  for (int s = 0; s < 4; ++s) {
    const int f = tid + s * 512;        // float4 index in tile, 0..2047
    const int r = f >> 4, c4 = f & 15;  // 16 float4 per 64-col row
    float4 v = reinterpret_cast<const float4*>(x)[R0 * 16 + f];
    short4 o;
    o.x = f2bf(v.x); o.y = f2bf(v.y); o.z = f2bf(v.z); o.w = f2bf(v.w);
    *reinterpret_cast<short4*>(&hb[r][c4 * 4]) = o;
  }
  __syncthreads();

  const short* W1b = Wb;
  const short* W2b = Wb + 32768;
  const short* W3b = Wb + 32768 + 262144;
  const short* W4b = Wb + 32768 + 262144 + 131072;

  mlp_layer<64, 8, true>(W1b, b1, hb, wm, wn, lane);   // 64 -> 512, ELU
  mlp_layer<512, 8, true>(W2b, b2, hb, wm, wn, lane);  // 512 -> 512, ELU
  mlp_layer<512, 4, true>(W3b, b3, hb, wm, wn, lane);  // 512 -> 256, ELU
  final_layer(W4b, b4, x, out, hb, wid, lane, R0);     // 256 -> 64, dot, -p^2
}

extern "C" void kernel_launch(void* const* d_in, const int* in_sizes, int n_in,
                              void* d_out, int out_size, void* d_ws, size_t ws_size,
                              hipStream_t stream) {
  const float* x  = (const float*)d_in[0];
  const float* W1 = (const float*)d_in[1];
  const float* b1 = (const float*)d_in[2];
  const float* W2 = (const float*)d_in[3];
  const float* b2 = (const float*)d_in[4];
  const float* W3 = (const float*)d_in[5];
  const float* b3 = (const float*)d_in[6];
  const float* W4 = (const float*)d_in[7];
  const float* b4 = (const float*)d_in[8];
  float* out = (float*)d_out;
  short* wsb = (short*)d_ws;  // bf16 weights: 442368 shorts = 884736 B

  cvtw_all_kernel<<<432, 256, 0, stream>>>(W1, W2, W3, W4, wsb);
  mlp_fused_kernel<<<512, 512, 0, stream>>>(x, wsb, b1, b2, b3, b4, out);
}

// Round 4
// 194.839 us; speedup vs baseline: 1.0789x; 1.0789x over previous
//
#include <hip/hip_runtime.h>

// out[b] = -(x[b] . z[b])^2,  z = MLP(x): 64 ->512(ELU)->512(ELU)->256(ELU)->64
// Fused bf16-MFMA kernel: 64 rows/block, 8 waves (1x8 col split), LDS 66.5KB
// -> 2 blocks/CU (4 waves/SIMD) for cross-block latency hiding.

#define DEVI __device__ __forceinline__

typedef __attribute__((ext_vector_type(4))) float f32x4;
typedef __attribute__((ext_vector_type(8))) short bf16x8;

#define PADW 520  // 512 + 8 shorts pad -> row stride 1040B == 4 banks mod 32
#define ROWS 64   // batch rows per block

DEVI short f2bf(float f) {  // round-to-nearest-even fp32 -> bf16 bits
  unsigned u = __float_as_uint(f);
  u = u + 0x7fffu + ((u >> 16) & 1u);
  return (short)(u >> 16);
}

// One fused conversion kernel: W1|W2|W3|W4 fp32 -> bf16 into contiguous d_ws.
// float4 region bounds: W1 [0,8192) W2 [8192,73728) W3 [73728,106496) W4 [106496,110592)
__global__ void cvtw_all_kernel(const float* __restrict__ W1, const float* __restrict__ W2,
                                const float* __restrict__ W3, const float* __restrict__ W4,
                                short* __restrict__ dst) {
  int i = blockIdx.x * blockDim.x + threadIdx.x;
  if (i >= 110592) return;
  const float* src;
  int off;
  if (i < 8192)        { src = W1; off = 0; }
  else if (i < 73728)  { src = W2; off = 8192; }
  else if (i < 106496) { src = W3; off = 73728; }
  else                 { src = W4; off = 106496; }
  float4 v = reinterpret_cast<const float4*>(src)[i - off];
  short4 o;
  o.x = f2bf(v.x); o.y = f2bf(v.y); o.z = f2bf(v.z); o.w = f2bf(v.w);
  reinterpret_cast<short4*>(dst)[i] = o;
}

// Hidden layer, wave grid 1x8: each wave = all 64 rows (4 row-tiles) x NCT col-tiles.
// A-frag: lane l -> row (l&15), k = (l>>4)*8 + j   (m92 layout, B^T weights)
// D: col = lane&15, row = (lane>>4)*4 + j          (m89/m91)
template<int K, int NCT, bool DO_ELU>
DEVI void mlp_layer(const short* __restrict__ Wb, const float* __restrict__ bias,
                    short (&hb)[ROWS][PADW], int wn, int lane) {
  const int lr = lane & 15, kg = lane >> 4;
  const int c0 = wn * (NCT * 16);    // NCT col-tiles of 16
  f32x4 acc[4][NCT] = {};
  for (int ks = 0; ks < K / 32; ++ks) {
    const int kk = ks * 32 + kg * 8;
    bf16x8 a[4], b[NCT];
#pragma unroll
    for (int rt = 0; rt < 4; ++rt)
      a[rt] = *reinterpret_cast<const bf16x8*>(&hb[rt * 16 + lr][kk]);
#pragma unroll
    for (int ct = 0; ct < NCT; ++ct)
      b[ct] = *reinterpret_cast<const bf16x8*>(&Wb[(c0 + ct * 16 + lr) * K + kk]);
#pragma unroll
    for (int rt = 0; rt < 4; ++rt)
#pragma unroll
      for (int ct = 0; ct < NCT; ++ct)
        acc[rt][ct] = __builtin_amdgcn_mfma_f32_16x16x32_bf16(a[rt], b[ct], acc[rt][ct], 0, 0, 0);
  }
  __syncthreads();  // all waves done reading input region before in-place overwrite
#pragma unroll
  for (int ct = 0; ct < NCT; ++ct) {
    const int col = c0 + ct * 16 + lr;
    const float bv = bias[col];
#pragma unroll
    for (int rt = 0; rt < 4; ++rt) {
#pragma unroll
      for (int j = 0; j < 4; ++j) {
        float v = acc[rt][ct][j] + bv;
        if (DO_ELU) v = v > 0.f ? v : (__expf(v) - 1.f);
        hb[rt * 16 + kg * 4 + j][col] = f2bf(v);
      }
    }
  }
  __syncthreads();  // outputs visible to all waves
}

// Layer 4 (256->64, no ELU) + fused dot with fp32 x + write -(dot)^2.
// Waves 0..3: 16 rows x all 64 cols each. Waves 4..7 exit (no barrier after).
DEVI void final_layer(const short* __restrict__ W4b, const float* __restrict__ b4,
                      const float* __restrict__ xg, float* __restrict__ out,
                      short (&hb)[ROWS][PADW], int wid, int lane, int R0) {
  const int lr = lane & 15, kg = lane >> 4;
  const int r0 = wid * 16;
  f32x4 acc[4] = {};
  for (int ks = 0; ks < 8; ++ks) {
    const int kk = ks * 32 + kg * 8;
    bf16x8 a = *reinterpret_cast<const bf16x8*>(&hb[r0 + lr][kk]);
#pragma unroll
    for (int ct = 0; ct < 4; ++ct) {
      bf16x8 b = *reinterpret_cast<const bf16x8*>(&W4b[(ct * 16 + lr) * 256 + kk]);
      acc[ct] = __builtin_amdgcn_mfma_f32_16x16x32_bf16(a, b, acc[ct], 0, 0, 0);
    }
  }
  float bv[4];
#pragma unroll
  for (int ct = 0; ct < 4; ++ct) bv[ct] = b4[ct * 16 + lr];
#pragma unroll
  for (int j = 0; j < 4; ++j) {
    const int gr = R0 + r0 + kg * 4 + j;  // global batch row
    float p = 0.f;
#pragma unroll
    for (int ct = 0; ct < 4; ++ct)
      p += (acc[ct][j] + bv[ct]) * xg[gr * 64 + ct * 16 + lr];
    p += __shfl_xor(p, 1);
    p += __shfl_xor(p, 2);
    p += __shfl_xor(p, 4);
    p += __shfl_xor(p, 8);
    if (lr == 0) out[gr] = -p * p;
  }
}

__global__ __launch_bounds__(512, 4)  // 4 waves/EU -> 2 blocks/CU of 512 thr
void mlp_fused_kernel(const float* __restrict__ x,
                      const short* __restrict__ Wb,
                      const float* __restrict__ b1, const float* __restrict__ b2,
                      const float* __restrict__ b3, const float* __restrict__ b4,
                      float* __restrict__ out) {
  __shared__ __align__(16) short hb[ROWS][PADW];
  const int tid = threadIdx.x;
  const int lane = tid & 63, wid = tid >> 6;
  const int R0 = blockIdx.x * ROWS;

  // Stage x tile -> bf16 LDS [64][64] (coalesced float4 loads, 2 per thread)
#pragma unroll
  for (int s = 0; s < 2; ++s) {
    const int f = tid + s * 512;        // float4 index in tile, 0..1023
    const int r = f >> 4, c4 = f & 15;  // 16 float4 per 64-col row
    float4 v = reinterpret_cast<const float4*>(x)[R0 * 16 + f];
    short4 o;
    o.x = f2bf(v.x); o.y = f2bf(v.y); o.z = f2bf(v.z); o.w = f2bf(v.w);
    *reinterpret_cast<short4*>(&hb[r][c4 * 4]) = o;
  }
  __syncthreads();

  const short* W1b = Wb;
  const short* W2b = Wb + 32768;
  const short* W3b = Wb + 32768 + 262144;
  const short* W4b = Wb + 32768 + 262144 + 131072;

  mlp_layer<64, 4, true>(W1b, b1, hb, wid, lane);   // 64 -> 512, ELU
  mlp_layer<512, 4, true>(W2b, b2, hb, wid, lane);  // 512 -> 512, ELU
  mlp_layer<512, 2, true>(W3b, b3, hb, wid, lane);  // 512 -> 256, ELU
  if (wid < 4)
    final_layer(W4b, b4, x, out, hb, wid, lane, R0);  // 256 -> 64, dot, -p^2
}

extern "C" void kernel_launch(void* const* d_in, const int* in_sizes, int n_in,
                              void* d_out, int out_size, void* d_ws, size_t ws_size,
                              hipStream_t stream) {
  const float* x  = (const float*)d_in[0];
  const float* W1 = (const float*)d_in[1];
  const float* b1 = (const float*)d_in[2];
  const float* W2 = (const float*)d_in[3];
  const float* b2 = (const float*)d_in[4];
  const float* W3 = (const float*)d_in[5];
  const float* b3 = (const float*)d_in[6];
  const float* W4 = (const float*)d_in[7];
  const float* b4 = (const float*)d_in[8];
  float* out = (float*)d_out;
  short* wsb = (short*)d_ws;  // bf16 weights: 442368 shorts = 884736 B

  cvtw_all_kernel<<<432, 256, 0, stream>>>(W1, W2, W3, W4, wsb);
  mlp_fused_kernel<<<1024, 512, 0, stream>>>(x, wsb, b1, b2, b3, b4, out);
}

// Round 6
// 191.623 us; speedup vs baseline: 1.0970x; 1.0168x over previous
//
#include <hip/hip_runtime.h>

// out[b] = -(x[b] . z[b])^2,  z = MLP(x): 64 ->512(ELU)->512(ELU)->256(ELU)->64
// m97-style structure: activations in LDS (in-place), weights double-buffered
// into LDS via async global_load_lds (BK=32), one barrier per K-step.
// 64 rows/block, 8 waves col-split, 1024 blocks. LDS 132KB -> 1 block/CU.

#define DEVI __device__ __forceinline__

typedef __attribute__((ext_vector_type(4))) float f32x4;
typedef __attribute__((ext_vector_type(8))) short bf16x8;

#define PADW 520  // hb row stride 1040B -> A-reads uniformly bank-spread
#define ROWS 64   // batch rows per block

DEVI short f2bf(float f) {  // round-to-nearest-even fp32 -> bf16 bits
  unsigned u = __float_as_uint(f);
  u = u + 0x7fffu + ((u >> 16) & 1u);
  return (short)(u >> 16);
}

// One fused conversion kernel: W1|W2|W3|W4 fp32 -> bf16 into contiguous d_ws.
__global__ void cvtw_all_kernel(const float* __restrict__ W1, const float* __restrict__ W2,
                                const float* __restrict__ W3, const float* __restrict__ W4,
                                short* __restrict__ dst) {
  int i = blockIdx.x * blockDim.x + threadIdx.x;
  if (i >= 110592) return;
  const float* src;
  int off;
  if (i < 8192)        { src = W1; off = 0; }
  else if (i < 73728)  { src = W2; off = 8192; }
  else if (i < 106496) { src = W3; off = 73728; }
  else                 { src = W4; off = 106496; }
  float4 v = reinterpret_cast<const float4*>(src)[i - off];
  short4 o;
  o.x = f2bf(v.x); o.y = f2bf(v.y); o.z = f2bf(v.z); o.w = f2bf(v.w);
  reinterpret_cast<short4*>(dst)[i] = o;
}

DEVI void gld16(const void* g, void* l) {  // async global -> LDS, 16B/lane
  __builtin_amdgcn_global_load_lds((const __attribute__((address_space(1))) void*)g,
                                   (__attribute__((address_space(3))) void*)l, 16, 0, 0);
}

// Stage K-slice `ks` (BK=32) of W[COLS][K] into wt tile [COLS][32] shorts.
// LDS dest is linear (global_load_lds requirement); bank-swizzle is applied on
// the GLOBAL source granule: LDS granule (c,g') holds source granule g = g'^((c>>1)&3).
// Reader must use the same XOR (rule #21: both-sides-or-neither).
template<int COLS, int K>
DEVI void stage_w(const short* __restrict__ W, int ks, short* dst, int tid) {
#pragma unroll
  for (int i = 0; i < COLS / 128; ++i) {
    const int G = i * 512 + tid;        // 16B granule index in tile
    const int c = G >> 2, gp = G & 3;   // col, LDS granule-within-row
    const int g = gp ^ ((c >> 1) & 3);  // source granule-within-row
    gld16(W + c * K + ks * 32 + g * 8, dst + G * 8);
  }
}

// Hidden layer: K-loop with double-buffered W tiles; in-place hb update.
// A-frag: lane l -> row (l&15), k=(l>>4)*8+j ; D: col=lane&15, row=(lane>>4)*4+j
template<int K, int NCT, int NEXT_COLS, int NEXT_K>
DEVI void hidden_layer(const short* __restrict__ W, const short* __restrict__ Wn,
                       const float* __restrict__ bias,
                       short (&hb)[ROWS][PADW], short* wta, short* wtb, int& cur,
                       int tid, int wid, int lr, int kg) {
  const int c0 = wid * (NCT * 16);
  const int swz = (kg ^ ((lr >> 1) & 3)) * 16;  // read-side granule XOR
  constexpr int NKS = K / 32;
  f32x4 acc[4][NCT] = {};
  for (int ks = 0; ks < NKS; ++ks) {
    short* nxt = cur ? wta : wtb;
    const short* src = cur ? wtb : wta;
    if (ks + 1 < NKS)
      stage_w<NCT * 128, K>(W, ks + 1, nxt, tid);       // prefetch next K-slice
    else if constexpr (NEXT_COLS > 0)
      stage_w<NEXT_COLS, NEXT_K>(Wn, 0, nxt, tid);      // prefetch next layer's slice 0
    const int kk = ks * 32 + kg * 8;
    bf16x8 a[4], b[NCT];
#pragma unroll
    for (int rt = 0; rt < 4; ++rt)
      a[rt] = *reinterpret_cast<const bf16x8*>(&hb[rt * 16 + lr][kk]);
#pragma unroll
    for (int ct = 0; ct < NCT; ++ct)
      b[ct] = *reinterpret_cast<const bf16x8*>(
          (const char*)src + (c0 + ct * 16 + lr) * 64 + swz);
#pragma unroll
    for (int rt = 0; rt < 4; ++rt)
#pragma unroll
      for (int ct = 0; ct < NCT; ++ct)
        acc[rt][ct] = __builtin_amdgcn_mfma_f32_16x16x32_bf16(a[rt], b[ct], acc[rt][ct], 0, 0, 0);
    __syncthreads();  // drains this step's stage loads; gates buffer swap + hb reuse
    cur ^= 1;
  }
  // epilogue: bias + ELU + bf16 write back to hb (in-place; K-loop barrier passed)
#pragma unroll
  for (int ct = 0; ct < NCT; ++ct) {
    const int col = c0 + ct * 16 + lr;
    const float bv = bias[col];
#pragma unroll
    for (int rt = 0; rt < 4; ++rt) {
#pragma unroll
      for (int j = 0; j < 4; ++j) {
        float v = acc[rt][ct][j] + bv;
        v = v > 0.f ? v : (__expf(v) - 1.f);
        hb[rt * 16 + kg * 4 + j][col] = f2bf(v);
      }
    }
  }
  __syncthreads();  // epilogue writes visible before next layer's A-reads
}

// Layer 4 (256->64, no ELU) + fused dot with fp32 x + write -(dot)^2.
// Waves 0..3: 16 rows x all 64 cols each; W4 read direct from global (small).
DEVI void final_layer(const short* __restrict__ W4b, const float* __restrict__ b4,
                      const float* __restrict__ xg, float* __restrict__ out,
                      short (&hb)[ROWS][PADW], int wid, int lane, int R0) {
  const int lr = lane & 15, kg = lane >> 4;
  const int r0 = wid * 16;
  f32x4 acc[4] = {};
  for (int ks = 0; ks < 8; ++ks) {
    const int kk = ks * 32 + kg * 8;
    bf16x8 a = *reinterpret_cast<const bf16x8*>(&hb[r0 + lr][kk]);
#pragma unroll
    for (int ct = 0; ct < 4; ++ct) {
      bf16x8 b = *reinterpret_cast<const bf16x8*>(&W4b[(ct * 16 + lr) * 256 + kk]);
      acc[ct] = __builtin_amdgcn_mfma_f32_16x16x32_bf16(a, b, acc[ct], 0, 0, 0);
    }
  }
  float bv[4];
#pragma unroll
  for (int ct = 0; ct < 4; ++ct) bv[ct] = b4[ct * 16 + lr];
#pragma unroll
  for (int j = 0; j < 4; ++j) {
    const int gr = R0 + r0 + kg * 4 + j;  // global batch row
    float p = 0.f;
#pragma unroll
    for (int ct = 0; ct < 4; ++ct)
      p += (acc[ct][j] + bv[ct]) * xg[gr * 64 + ct * 16 + lr];
    p += __shfl_xor(p, 1);
    p += __shfl_xor(p, 2);
    p += __shfl_xor(p, 4);
    p += __shfl_xor(p, 8);
    if (lr == 0) out[gr] = -p * p;
  }
}

__global__ __launch_bounds__(512, 2)  // 256-reg budget: room to pipeline
void mlp_fused_kernel(const float* __restrict__ x,
                      const short* __restrict__ Wb,
                      const float* __restrict__ b1, const float* __restrict__ b2,
                      const float* __restrict__ b3, const float* __restrict__ b4,
                      float* __restrict__ out) {
  __shared__ __align__(16) short hb[ROWS][PADW];      // 66,560 B activations
  __shared__ __align__(16) short wt[2][512 * 32];     // 65,536 B W double-buffer
  const int tid = threadIdx.x;
  const int lane = tid & 63, wid = tid >> 6;
  const int lr = lane & 15, kg = lane >> 4;
  const int R0 = blockIdx.x * ROWS;

  const short* W1b = Wb;
  const short* W2b = Wb + 32768;
  const short* W3b = Wb + 32768 + 262144;
  const short* W4b = Wb + 32768 + 262144 + 131072;

  // Stage x tile -> bf16 LDS [64][64] (coalesced float4 loads, 2 per thread)
#pragma unroll
  for (int s = 0; s < 2; ++s) {
    const int f = tid + s * 512;        // float4 index in tile, 0..1023
    const int r = f >> 4, c4 = f & 15;  // 16 float4 per 64-col row
    float4 v = reinterpret_cast<const float4*>(x)[R0 * 16 + f];
    short4 o;
    o.x = f2bf(v.x); o.y = f2bf(v.y); o.z = f2bf(v.z); o.w = f2bf(v.w);
    *reinterpret_cast<short4*>(&hb[r][c4 * 4]) = o;
  }
  stage_w<512, 64>(W1b, 0, wt[0], tid);  // L1 slice 0
  __syncthreads();                       // x staged + W1 slice 0 landed

  int cur = 0;
  hidden_layer<64, 4, 512, 512>(W1b, W2b, b1, hb, wt[0], wt[1], cur, tid, wid, lr, kg);
  hidden_layer<512, 4, 256, 512>(W2b, W3b, b2, hb, wt[0], wt[1], cur, tid, wid, lr, kg);
  hidden_layer<512, 2, 0, 0>(W3b, nullptr, b3, hb, wt[0], wt[1], cur, tid, wid, lr, kg);
  if (wid < 4)
    final_layer(W4b, b4, x, out, hb, wid, lane, R0);  // 256 -> 64, dot, -p^2
}

extern "C" void kernel_launch(void* const* d_in, const int* in_sizes, int n_in,
                              void* d_out, int out_size, void* d_ws, size_t ws_size,
                              hipStream_t stream) {
  const float* x  = (const float*)d_in[0];
  const float* W1 = (const float*)d_in[1];
  const float* b1 = (const float*)d_in[2];
  const float* W2 = (const float*)d_in[3];
  const float* b2 = (const float*)d_in[4];
  const float* W3 = (const float*)d_in[5];
  const float* b3 = (const float*)d_in[6];
  const float* W4 = (const float*)d_in[7];
  const float* b4 = (const float*)d_in[8];
  float* out = (float*)d_out;
  short* wsb = (short*)d_ws;  // bf16 weights: 442368 shorts = 884736 B

  cvtw_all_kernel<<<432, 256, 0, stream>>>(W1, W2, W3, W4, wsb);
  mlp_fused_kernel<<<1024, 512, 0, stream>>>(x, wsb, b1, b2, b3, b4, out);
}